// Round 1
// 358.293 us; speedup vs baseline: 1.0989x; 1.0989x over previous
//
#include <hip/hip_runtime.h>

#define BLK 256
#define EPT 4                      // elements per thread
#define WLDS (BLK * EPT * 8)       // 8192 floats = 32 KB weight staging

// 4 elems/thread. 8 consecutive lanes = one 32-elem e8m0 block.
// Decision path (e, xs, ord, codes, scales) kept bit-identical to the
// previously-passing kernel: exact a/6.0f divide, libm log2f, ceilf, and
// 2^-e built by bit construction (exact). Sigmoid/normalize switched to
// v_exp/v_rcp (weights move by <=1e-6, far under tolerance).
__global__ __launch_bounds__(BLK) void fp4_kernel(
    const float* __restrict__ x,
    const float* __restrict__ delta_raw,
    const float* __restrict__ bounds_base,
    const float* __restrict__ values_table,
    float* __restrict__ out, long long N)
{
    const int tid = threadIdx.x;
    const long long base = (long long)blockIdx.x * (BLK * EPT);
    const long long g0 = base + (long long)(tid * EPT);

    __shared__ float s_vals[8];
    __shared__ __align__(16) float s_w[WLDS];   // XOR-swizzled staging

    if (tid < 8) s_vals[tid] = values_table[tid];

    // wave-uniform scalars (compiler scalarizes these loads)
    const float ht = 0.5f * tanhf(delta_raw[0]);
    const float C = 14.426950408889634f;        // (1/TAU) * log2(e)
    float sb[7], cb[7];
#pragma unroll
    for (int j = 0; j < 7; ++j) { sb[j] = bounds_base[j] + ht; cb[j] = sb[j] * C; }
    float vt[8];
#pragma unroll
    for (int k = 0; k < 8; ++k) vt[k] = values_table[k];

    __syncthreads();

    const float4 xv = *reinterpret_cast<const float4*>(x + g0);
    const float xe[EPT] = {xv.x, xv.y, xv.z, xv.w};

    // per-32-block amax: local max of 4, butterfly over the 8-lane group
    float a = fmaxf(fmaxf(fabsf(xe[0]), fabsf(xe[1])),
                    fmaxf(fabsf(xe[2]), fabsf(xe[3])));
    a = fmaxf(a, __shfl_xor(a, 1));
    a = fmaxf(a, __shfl_xor(a, 2));
    a = fmaxf(a, __shfl_xor(a, 4));

    const float descale = a / 6.0f;                         // exact div (ref-match)
    const float e = ceilf(fmaxf(log2f(descale), -127.0f));  // libm log2 (ref-match)
    const int ie = (int)e;                                  // e in [-127,126]
    const float inv_scale = __int_as_float((127 - ie) << 23);   // 2^-e exact, normal
    const float scale = (ie == -127) ? __int_as_float(0x00400000)   // 2^-127 subnormal
                                     : __int_as_float((ie + 127) << 23);

    const int wkey = (tid & 7) << 2;
    float ys[EPT], cd[EPT];

#pragma unroll
    for (int i = 0; i < EPT; ++i) {
        const float xs = xe[i] * inv_scale;   // exact: mult by power of two
        const float xa = fabsf(xs);

        int ord = 0;
#pragma unroll
        for (int j = 0; j < 7; ++j) ord += (xa > sb[j]) ? 1 : 0;   // exact compares

        const float xac = xa * C;
        float p[7];
#pragma unroll
        for (int j = 0; j < 7; ++j) {
            const float ex = exp2f(cb[j] - xac);        // = exp((sb-xa)/tau), v_exp
            p[j] = __builtin_amdgcn_rcpf(1.0f + ex);    // sigmoid
        }

        float w[8];
        w[0] = 1.0f - p[0];
#pragma unroll
        for (int j = 1; j < 7; ++j) w[j] = p[j - 1] - p[j];
        w[7] = p[6];

        float sum = 0.0f;
#pragma unroll
        for (int k = 0; k < 8; ++k) { w[k] = fmaxf(w[k], 0.0f); sum += w[k]; }
        const float inv = __builtin_amdgcn_rcpf(sum + 1e-8f);

        float abs_soft = 0.0f;
#pragma unroll
        for (int k = 0; k < 8; ++k) { w[k] *= inv; abs_soft += w[k] * vt[k]; }

        const float abs_hard = s_vals[ord];                   // LDS dynamic index
        const float abs_mix = abs_soft + (abs_hard - abs_soft);  // faithful ST expr
        ys[i] = ((xs >= 0.0f) ? abs_mix : -abs_mix) * scale;
        cd[i] = (float)(((xs < 0.0f) ? 8 : 0) | ord);

        // stage weights, XOR-swizzled so both b128 writes and scalar reads are
        // conflict-free: physical = logical ^ ((owner_thread&7)<<2)
        const int f = (tid * EPT + i) * 8;
        *reinterpret_cast<float4*>(&s_w[(f + 0) ^ wkey]) =
            make_float4(w[0], w[1], w[2], w[3]);
        *reinterpret_cast<float4*>(&s_w[(f + 4) ^ wkey]) =
            make_float4(w[4], w[5], w[6], w[7]);
    }

    // vector stores: y and codes regions are 16B-aligned (g0 % 4 == 0, N % 4 == 0)
    *reinterpret_cast<float4*>(out + g0)     = make_float4(ys[0], ys[1], ys[2], ys[3]);
    *reinterpret_cast<float4*>(out + N + g0) = make_float4(cd[0], cd[1], cd[2], cd[3]);
    if ((tid & 7) == 0) out[2 * N + (g0 >> 5)] = e + 127.0f;
    if (blockIdx.x == 0 && tid < 7) out[2 * N + (N >> 5) + tid] = sb[tid];

    __syncthreads();

    // coalesced scalar readback (weights base misaligned by 3 floats -> keep dword
    // stores, which are always aligned). Logical g = tid + 256k; owner = g>>5;
    // physical = g ^ ((owner&7)<<2). (tid>>5)&7 is k-invariant -> hoist.
    const long long wbase = 2 * N + (N >> 5) + 7 + (long long)blockIdx.x * WLDS;
    const int rbase = tid ^ (((tid >> 5) & 7) << 2);
#pragma unroll
    for (int k = 0; k < 32; ++k) {
        out[wbase + tid + (k << 8)] = s_w[rbase + (k << 8)];
    }
}

extern "C" void kernel_launch(void* const* d_in, const int* in_sizes, int n_in,
                              void* d_out, int out_size, void* d_ws, size_t ws_size,
                              hipStream_t stream) {
    const float* x      = (const float*)d_in[0];
    const float* delta  = (const float*)d_in[1];
    const float* bounds = (const float*)d_in[2];
    const float* vals   = (const float*)d_in[3];
    float* out = (float*)d_out;
    const long long N = (long long)in_sizes[0];   // 8388608 = 2^23, divisible by 1024
    const int nblocks = (int)(N / (BLK * EPT));
    fp4_kernel<<<nblocks, BLK, 0, stream>>>(x, delta, bounds, vals, out, N);
}